// Round 4
// baseline (952.271 us; speedup 1.0000x reference)
//
#include <hip/hip_runtime.h>
#include <hip/hip_bf16.h>

// HardMemory: x[32,512,64,64] f32, memory[1024,512] f32.
// sim = cos(x_pixel, mem_row); out[b,c,n] = memory[argmax][c] * (max>0.8)
// Pipeline: (1) normalize memory -> bf16, (2) MFMA GEMM + fused max/argmax,
// (3) masked gather epilogue, wave-sequential stores.

typedef __attribute__((ext_vector_type(8))) short short8;   // 8 bf16 (4 VGPRs)
typedef __attribute__((ext_vector_type(4))) float f32x4;
typedef __attribute__((ext_vector_type(4))) int   i32x4;

#define THRESH 0.8f
#define EPSN   1e-12f

__device__ __forceinline__ short f2bf(float f) {
    union { float f; unsigned u; } v; v.f = f;
    unsigned r = v.u + 0x7fffu + ((v.u >> 16) & 1u);   // RNE
    return (short)(r >> 16);
}

// ---------------- kernel 1: normalize memory rows -> bf16 ----------------
__global__ __launch_bounds__(256) void norm_mem_kernel(
        const float* __restrict__ mem, short* __restrict__ mem_bf) {
    const int row = blockIdx.x;          // 1024
    const int t   = threadIdx.x;         // 256
    const float* r = mem + (size_t)row * 512;
    float v0 = r[t], v1 = r[t + 256];
    float ss = v0 * v0 + v1 * v1;
    #pragma unroll
    for (int off = 32; off; off >>= 1) ss += __shfl_down(ss, off, 64);
    __shared__ float part[4];
    __shared__ float rinv_s;
    if ((t & 63) == 0) part[t >> 6] = ss;
    __syncthreads();
    if (t == 0) {
        float s = part[0] + part[1] + part[2] + part[3];
        rinv_s = 1.0f / fmaxf(sqrtf(s), EPSN);
    }
    __syncthreads();
    float rinv = rinv_s;
    mem_bf[(size_t)row * 512 + t]       = f2bf(v0 * rinv);
    mem_bf[(size_t)row * 512 + t + 256] = f2bf(v1 * rinv);
}

// ---------------- kernel 2: GEMM + fused row max/argmax ----------------
// Block: 64 pixels x all 1024 mems. 256 threads = 4 waves.
// Wave tile: 64 pixels x 32 mems -> 8 mfma_f32_16x16x32_bf16 per K-step of 32,
// fed by 4 LDS A-reads + 2 global B-reads (1-step register prefetch).
// mc loop: 8 chunks of 128 mems (waves split mems; each B row read once/block).
// Register math: acc 32 (AGPR) + B cur/next 16 + A 16 + max/argmax 32 + addr
// ~= 115 VGPR -> fits the 128-VGPR half-file, NO spill.
__global__ __launch_bounds__(256, 2) void simmax_kernel(
        const float* __restrict__ x, const short* __restrict__ memn,
        int* __restrict__ selv) {
    __shared__ short xs[64 * 512];       // 64 KiB, A-tile pre-fragmented
    __shared__ float part[4][64];        // per-wave partial ||x||^2
    __shared__ float redv[4][64];        // per-wave max
    __shared__ int   redi[4][64];        // per-wave argmax

    const int t  = threadIdx.x;          // 0..255
    const int b  = blockIdx.y;           // 32
    const int n0 = blockIdx.x * 64;      // 64 pixel tiles
    const int p  = t & 63;
    const int w  = t >> 6;               // wave 0..3

    // ---- stage X tile: x[b, c, n0+p] -> xs[(c/8)*64 + p][c%8] as bf16 ----
    const float* xb = x + ((size_t)b * 512) * 4096 + n0 + p;
    float ss = 0.f;
    for (int oct = w; oct < 64; oct += 4) {
        short8 pk;
        #pragma unroll
        for (int i = 0; i < 8; ++i) {
            float v = xb[(size_t)(oct * 8 + i) * 4096];
            ss += v * v;
            pk[i] = f2bf(v);
        }
        *(short8*)&xs[(oct * 64 + p) * 8] = pk;
    }
    part[w][p] = ss;
    __syncthreads();

    float xnorm_reg = 1.0f;
    if (t < 64) {
        float s = part[0][t] + part[1][t] + part[2][t] + part[3][t];
        xnorm_reg = fmaxf(sqrtf(s), EPSN);
    }

    const int lane = t & 63;
    const int quad = lane >> 4;
    const int l15  = lane & 15;

    float runv[4][4];
    int   runi[4][4];
    #pragma unroll
    for (int i = 0; i < 4; ++i)
        #pragma unroll
        for (int r = 0; r < 4; ++r) { runv[i][r] = -1e30f; runi[i][r] = 0; }

    for (int mc = 0; mc < 8; ++mc) {
        f32x4 acc[4][2];
        #pragma unroll
        for (int i = 0; i < 4; ++i)
            #pragma unroll
            for (int j = 0; j < 2; ++j) acc[i][j] = (f32x4){0.f, 0.f, 0.f, 0.f};

        const int mb = mc * 128 + w * 32;          // this wave's 32 mems
        const short* bptr = memn + (size_t)(mb + l15) * 512 + quad * 8;

        short8 bcur[2];
        #pragma unroll
        for (int j = 0; j < 2; ++j)
            bcur[j] = *(const short8*)(bptr + j * 8192);   // rows 16 apart

        #pragma unroll
        for (int kk = 0; kk < 512; kk += 32) {
            short8 bnxt[2];
            if (kk + 32 < 512) {
                #pragma unroll
                for (int j = 0; j < 2; ++j)
                    bnxt[j] = *(const short8*)(bptr + j * 8192 + kk + 32);
            }
            const int oct = (kk >> 3) + quad;
            short8 a[4];
            #pragma unroll
            for (int i = 0; i < 4; ++i)
                a[i] = *(const short8*)&xs[(oct * 64 + i * 16 + l15) * 8];
            #pragma unroll
            for (int i = 0; i < 4; ++i)
                #pragma unroll
                for (int j = 0; j < 2; ++j)
                    acc[i][j] = __builtin_amdgcn_mfma_f32_16x16x32_bf16(
                        a[i], bcur[j], acc[i][j], 0, 0, 0);
            if (kk + 32 < 512) {
                #pragma unroll
                for (int j = 0; j < 2; ++j) bcur[j] = bnxt[j];
            }
        }

        #pragma unroll
        for (int i = 0; i < 4; ++i)
            #pragma unroll
            for (int j = 0; j < 2; ++j) {        // ascending col within wave
                const int cb = mb + j * 16 + l15;
                #pragma unroll
                for (int r = 0; r < 4; ++r) {
                    float v = acc[i][j][r];
                    if (v > runv[i][r]) { runv[i][r] = v; runi[i][r] = cb; }
                }
            }
    }

    // ---- cross-lane max/argmax (cols live on 16 lanes of each quad) ----
    #pragma unroll
    for (int i = 0; i < 4; ++i)
        #pragma unroll
        for (int r = 0; r < 4; ++r) {
            float v = runv[i][r]; int ix = runi[i][r];
            #pragma unroll
            for (int off = 1; off < 16; off <<= 1) {
                float ov = __shfl_xor(v, off, 64);
                int   oi = __shfl_xor(ix, off, 64);
                if (ov > v || (ov == v && oi < ix)) { v = ov; ix = oi; }
            }
            if (l15 == 0) {
                const int pl = i * 16 + quad * 4 + r;   // pixel row 0..63
                redv[w][pl] = v;
                redi[w][pl] = ix;
            }
        }

    __syncthreads();
    if (t < 64) {
        float v = redv[0][t]; int ix = redi[0][t];
        #pragma unroll
        for (int c = 1; c < 4; ++c) {            // index-based tie-break
            float ov = redv[c][t]; int oi = redi[c][t];
            if (ov > v || (ov == v && oi < ix)) { v = ov; ix = oi; }
        }
        float maxval = v / xnorm_reg;
        selv[(size_t)b * 4096 + n0 + t] = (maxval > THRESH) ? ix : -1;
    }
}

// ---------------- kernel 3: masked gather, wave-sequential stores ----------------
// Each wave owns one contiguous output row out[b, c, 0..4096) = 16 KiB and
// streams it: dense instantaneous write footprint (page-friendly).
__global__ __launch_bounds__(256) void scatter_kernel(
        const float* __restrict__ mem, const int* __restrict__ selv,
        float* __restrict__ out) {
    const int t    = threadIdx.x;        // 256
    const int w    = t >> 6;             // wave 0..3
    const int lane = t & 63;
    const int cg   = blockIdx.x;         // 128 groups of 4 c
    const int b    = blockIdx.y;         // 32
    const int c    = cg * 4 + w;         // this wave's channel
    const int* sb  = selv + (size_t)b * 4096;
    const float* mc_ = mem + c;
    float* ob = out + ((size_t)b * 512 + c) * 4096;
    #pragma unroll
    for (int rd = 0; rd < 16; ++rd) {
        const int n = rd * 256 + lane * 4;
        i32x4 sel = *(const i32x4*)&sb[n];
        f32x4 v;
        v.x = (sel.x < 0) ? 0.f : mc_[(size_t)sel.x * 512];
        v.y = (sel.y < 0) ? 0.f : mc_[(size_t)sel.y * 512];
        v.z = (sel.z < 0) ? 0.f : mc_[(size_t)sel.z * 512];
        v.w = (sel.w < 0) ? 0.f : mc_[(size_t)sel.w * 512];
        __builtin_nontemporal_store(v, (f32x4*)&ob[n]);
    }
}

extern "C" void kernel_launch(void* const* d_in, const int* in_sizes, int n_in,
                              void* d_out, int out_size, void* d_ws, size_t ws_size,
                              hipStream_t stream) {
    const float* x   = (const float*)d_in[0];   // [32,512,64,64]
    const float* mem = (const float*)d_in[1];   // [1024,512]
    short* mem_bf = (short*)d_ws;                       // 1 MiB bf16 normalized
    int*   selv   = (int*)((char*)d_ws + (1 << 20));    // 512 KiB selections
    float* out    = (float*)d_out;

    norm_mem_kernel<<<dim3(1024), dim3(256), 0, stream>>>(mem, mem_bf);
    simmax_kernel<<<dim3(64, 32), dim3(256), 0, stream>>>(x, mem_bf, selv);
    scatter_kernel<<<dim3(128, 32), dim3(256), 0, stream>>>(mem, selv, out);
}

// Round 5
// 716.091 us; speedup vs baseline: 1.3298x; 1.3298x over previous
//
#include <hip/hip_runtime.h>
#include <hip/hip_bf16.h>

// HardMemory: x[32,512,64,64] f32, memory[1024,512] f32.
// sim = cos(x_pixel, mem_row); out[b,c,n] = memory[argmax][c] * (max>0.8)
// Pipeline: (1) normalize memory -> bf16, (2) MFMA GEMM + fused max/argmax,
// (3) masked gather epilogue, wave-sequential stores.

typedef __attribute__((ext_vector_type(8))) short short8;   // 8 bf16 (4 VGPRs)
typedef __attribute__((ext_vector_type(4))) float f32x4;
typedef __attribute__((ext_vector_type(4))) int   i32x4;

#define THRESH 0.8f
#define EPSN   1e-12f

__device__ __forceinline__ short f2bf(float f) {
    union { float f; unsigned u; } v; v.f = f;
    unsigned r = v.u + 0x7fffu + ((v.u >> 16) & 1u);   // RNE
    return (short)(r >> 16);
}

// ---------------- kernel 1: normalize memory rows -> bf16 ----------------
__global__ __launch_bounds__(256) void norm_mem_kernel(
        const float* __restrict__ mem, short* __restrict__ mem_bf) {
    const int row = blockIdx.x;          // 1024
    const int t   = threadIdx.x;         // 256
    const float* r = mem + (size_t)row * 512;
    float v0 = r[t], v1 = r[t + 256];
    float ss = v0 * v0 + v1 * v1;
    #pragma unroll
    for (int off = 32; off; off >>= 1) ss += __shfl_down(ss, off, 64);
    __shared__ float part[4];
    __shared__ float rinv_s;
    if ((t & 63) == 0) part[t >> 6] = ss;
    __syncthreads();
    if (t == 0) {
        float s = part[0] + part[1] + part[2] + part[3];
        rinv_s = 1.0f / fmaxf(sqrtf(s), EPSN);
    }
    __syncthreads();
    float rinv = rinv_s;
    mem_bf[(size_t)row * 512 + t]       = f2bf(v0 * rinv);
    mem_bf[(size_t)row * 512 + t + 256] = f2bf(v1 * rinv);
}

// ---------------- kernel 2: GEMM + fused row max/argmax ----------------
// Block: 64 pixels x all 1024 mems. 256 threads = 4 waves.
// Wave tile: 64 pixels x 32 mems -> 8 mfma_f32_16x16x32_bf16 per K-step of 32,
// fed by 4 LDS A-reads + 2 global B-reads (1-step register prefetch).
// kk loop is FORCIBLY ROLLED (#pragma unroll 1): full unroll let the
// scheduler hoist 16 iterations of loads -> VGPR live-range explosion ->
// 850 MB of scratch spill traffic (rounds 2-4). Rolled body needs ~100 regs.
__global__ __launch_bounds__(256, 2) void simmax_kernel(
        const float* __restrict__ x, const short* __restrict__ memn,
        int* __restrict__ selv) {
    __shared__ short xs[64 * 512];       // 64 KiB, A-tile pre-fragmented
    __shared__ float part[4][64];        // per-wave partial ||x||^2
    __shared__ float redv[4][64];        // per-wave max
    __shared__ int   redi[4][64];        // per-wave argmax

    const int t  = threadIdx.x;          // 0..255
    const int b  = blockIdx.y;           // 32
    const int n0 = blockIdx.x * 64;      // 64 pixel tiles
    const int p  = t & 63;
    const int w  = t >> 6;               // wave 0..3

    // ---- stage X tile: x[b, c, n0+p] -> xs[(c/8)*64 + p][c%8] as bf16 ----
    const float* xb = x + ((size_t)b * 512) * 4096 + n0 + p;
    float ss = 0.f;
    for (int oct = w; oct < 64; oct += 4) {
        short8 pk;
        #pragma unroll
        for (int i = 0; i < 8; ++i) {
            float v = xb[(size_t)(oct * 8 + i) * 4096];
            ss += v * v;
            pk[i] = f2bf(v);
        }
        *(short8*)&xs[(oct * 64 + p) * 8] = pk;
    }
    part[w][p] = ss;
    __syncthreads();

    float xnorm_reg = 1.0f;
    if (t < 64) {
        float s = part[0][t] + part[1][t] + part[2][t] + part[3][t];
        xnorm_reg = fmaxf(sqrtf(s), EPSN);
    }

    const int lane = t & 63;
    const int quad = lane >> 4;
    const int l15  = lane & 15;

    float runv[4][4];
    int   runi[4][4];
    #pragma unroll
    for (int i = 0; i < 4; ++i)
        #pragma unroll
        for (int r = 0; r < 4; ++r) { runv[i][r] = -1e30f; runi[i][r] = 0; }

    #pragma unroll 1
    for (int mc = 0; mc < 8; ++mc) {
        f32x4 acc[4][2];
        #pragma unroll
        for (int i = 0; i < 4; ++i)
            #pragma unroll
            for (int j = 0; j < 2; ++j) acc[i][j] = (f32x4){0.f, 0.f, 0.f, 0.f};

        const int mb = mc * 128 + w * 32;          // this wave's 32 mems
        const short* bptr = memn + (size_t)(mb + l15) * 512 + quad * 8;

        short8 bcur[2];
        #pragma unroll
        for (int j = 0; j < 2; ++j)
            bcur[j] = *(const short8*)(bptr + j * 8192);   // rows 16 apart

        // NOTE: last prefetch reads <=48 B past mem_bf into the selv region
        // of d_ws (in-bounds of the allocation, values unused).
        #pragma unroll 1
        for (int kk = 0; kk < 512; kk += 32) {
            short8 bnxt[2];
            #pragma unroll
            for (int j = 0; j < 2; ++j)
                bnxt[j] = *(const short8*)(bptr + j * 8192 + kk + 32);
            const int oct = (kk >> 3) + quad;
            short8 a[4];
            #pragma unroll
            for (int i = 0; i < 4; ++i)
                a[i] = *(const short8*)&xs[(oct * 64 + i * 16 + l15) * 8];
            #pragma unroll
            for (int i = 0; i < 4; ++i)
                #pragma unroll
                for (int j = 0; j < 2; ++j)
                    acc[i][j] = __builtin_amdgcn_mfma_f32_16x16x32_bf16(
                        a[i], bcur[j], acc[i][j], 0, 0, 0);
            #pragma unroll
            for (int j = 0; j < 2; ++j) bcur[j] = bnxt[j];
        }

        #pragma unroll
        for (int i = 0; i < 4; ++i)
            #pragma unroll
            for (int j = 0; j < 2; ++j) {        // ascending col within wave
                const int cb = mb + j * 16 + l15;
                #pragma unroll
                for (int r = 0; r < 4; ++r) {
                    float v = acc[i][j][r];
                    if (v > runv[i][r]) { runv[i][r] = v; runi[i][r] = cb; }
                }
            }
    }

    // ---- cross-lane max/argmax (cols live on 16 lanes of each quad) ----
    #pragma unroll
    for (int i = 0; i < 4; ++i)
        #pragma unroll
        for (int r = 0; r < 4; ++r) {
            float v = runv[i][r]; int ix = runi[i][r];
            #pragma unroll
            for (int off = 1; off < 16; off <<= 1) {
                float ov = __shfl_xor(v, off, 64);
                int   oi = __shfl_xor(ix, off, 64);
                if (ov > v || (ov == v && oi < ix)) { v = ov; ix = oi; }
            }
            if (l15 == 0) {
                const int pl = i * 16 + quad * 4 + r;   // pixel row 0..63
                redv[w][pl] = v;
                redi[w][pl] = ix;
            }
        }

    __syncthreads();
    if (t < 64) {
        float v = redv[0][t]; int ix = redi[0][t];
        #pragma unroll
        for (int c = 1; c < 4; ++c) {            // index-based tie-break
            float ov = redv[c][t]; int oi = redi[c][t];
            if (ov > v || (ov == v && oi < ix)) { v = ov; ix = oi; }
        }
        float maxval = v / xnorm_reg;
        selv[(size_t)b * 4096 + n0 + t] = (maxval > THRESH) ? ix : -1;
    }
}

// ---------------- kernel 3: masked gather, wave-sequential stores ----------------
// Each wave owns one contiguous output row out[b, c, 0..4096) = 16 KiB and
// streams it: dense instantaneous write footprint (page-friendly).
__global__ __launch_bounds__(256) void scatter_kernel(
        const float* __restrict__ mem, const int* __restrict__ selv,
        float* __restrict__ out) {
    const int t    = threadIdx.x;        // 256
    const int w    = t >> 6;             // wave 0..3
    const int lane = t & 63;
    const int cg   = blockIdx.x;         // 128 groups of 4 c
    const int b    = blockIdx.y;         // 32
    const int c    = cg * 4 + w;         // this wave's channel
    const int* sb  = selv + (size_t)b * 4096;
    const float* mc_ = mem + c;
    float* ob = out + ((size_t)b * 512 + c) * 4096;
    #pragma unroll
    for (int rd = 0; rd < 16; ++rd) {
        const int n = rd * 256 + lane * 4;
        i32x4 sel = *(const i32x4*)&sb[n];
        f32x4 v;
        v.x = (sel.x < 0) ? 0.f : mc_[(size_t)sel.x * 512];
        v.y = (sel.y < 0) ? 0.f : mc_[(size_t)sel.y * 512];
        v.z = (sel.z < 0) ? 0.f : mc_[(size_t)sel.z * 512];
        v.w = (sel.w < 0) ? 0.f : mc_[(size_t)sel.w * 512];
        __builtin_nontemporal_store(v, (f32x4*)&ob[n]);
    }
}

extern "C" void kernel_launch(void* const* d_in, const int* in_sizes, int n_in,
                              void* d_out, int out_size, void* d_ws, size_t ws_size,
                              hipStream_t stream) {
    const float* x   = (const float*)d_in[0];   // [32,512,64,64]
    const float* mem = (const float*)d_in[1];   // [1024,512]
    short* mem_bf = (short*)d_ws;                       // 1 MiB bf16 normalized
    int*   selv   = (int*)((char*)d_ws + (1 << 20));    // 512 KiB selections
    float* out    = (float*)d_out;

    norm_mem_kernel<<<dim3(1024), dim3(256), 0, stream>>>(mem, mem_bf);
    simmax_kernel<<<dim3(64, 32), dim3(256), 0, stream>>>(x, mem_bf, selv);
    scatter_kernel<<<dim3(128, 32), dim3(256), 0, stream>>>(mem, selv, out);
}